// Round 2
// baseline (115.857 us; speedup 1.0000x reference)
//
#include <hip/hip_runtime.h>
#include <math.h>

#define F_    16
#define NV_   4096
#define NT_   512
#define M_    4096
#define PPF_  (NV_ + NT_)        // 4608 points per frame
#define NPTS_ (F_ * PPF_)        // 73728 total points
#define SCALE_INV 10.0f          // 1 / 0.1

#define TPB    256
#define PPT    8                 // points per thread (amortize LDS broadcast reads)
#define PPB    (TPB * PPT)       // 2048 points per block
#define NPB    (NPTS_ / PPB)     // 36 point-blocks
#define CHUNK  128               // model points per chunk
#define NCHUNK (M_ / CHUNK)      // 32 chunks -> grid 36x32 = 1152 blocks

// ---------------------------------------------------------------- pose math
__device__ inline void rot_from_omega(float ox, float oy, float oz, float dt,
                                      float* R) {
    // R = I + sin(theta*dt)*S + (1-cos(theta*dt))*S^2,  S = skew(omega/max(theta,1e-8))
    float theta = sqrtf(ox * ox + oy * oy + oz * oz);
    float inv = 1.0f / fmaxf(theta, 1e-8f);
    float ax = ox * inv, ay = oy * inv, az = oz * inv;
    float s = sinf(theta * dt);
    float c = 1.0f - cosf(theta * dt);
    R[0] = 1.0f - c * (ay * ay + az * az);
    R[1] = -s * az + c * ax * ay;
    R[2] =  s * ay + c * ax * az;
    R[3] =  s * az + c * ax * ay;
    R[4] = 1.0f - c * (ax * ax + az * az);
    R[5] = -s * ax + c * ay * az;
    R[6] = -s * ay + c * ax * az;
    R[7] =  s * ax + c * ay * az;
    R[8] = 1.0f - c * (ax * ax + ay * ay);
}

__device__ inline void compute_pose(int f, const float* state, const float* phys,
                                    const float* dts, float* t, float* R) {
    t[0] = state[0]; t[1] = state[1]; t[2] = state[2];
    rot_from_omega(state[3], state[4], state[5], 1.0f, R);
    for (int i = 1; i <= f; ++i) {
        float dt = dts[i];
        t[0] += phys[i * 12 + 6] * dt;
        t[1] += phys[i * 12 + 7] * dt;
        t[2] += phys[i * 12 + 8] * dt;
        float Rs[9];
        rot_from_omega(phys[i * 12 + 9], phys[i * 12 + 10], phys[i * 12 + 11], dt, Rs);
        float Rn[9];
        for (int r = 0; r < 3; ++r)
            for (int c2 = 0; c2 < 3; ++c2)
                Rn[r * 3 + c2] = Rs[r * 3 + 0] * R[0 + c2] +
                                 Rs[r * 3 + 1] * R[3 + c2] +
                                 Rs[r * 3 + 2] * R[6 + c2];
        for (int j = 0; j < 9; ++j) R[j] = Rn[j];
    }
}

// ---------------------------------------------------------------- main kernel
// grid (NPB, NCHUNK). Each block: 2048 points x 128-model-point chunk.
// Poses computed redundantly per block (16 threads, <=15 chain steps).
// Writes per-chunk min distance to partials[ch][pt].
__global__ __launch_bounds__(TPB) void chamfer_main(
    const float* __restrict__ state, const float* __restrict__ model,
    const float* __restrict__ vis, const float* __restrict__ tac,
    const float* __restrict__ phys, const float* __restrict__ dts,
    float* __restrict__ partials) {
    __shared__ float4 sfeat[CHUNK];
    __shared__ float sposes[F_ * 12];
    const int pb = blockIdx.x;
    const int ch = blockIdx.y;
    const int mbase = ch * CHUNK;

    // poses (redundant per block; tiny)
    if (threadIdx.x < F_) {
        float t[3], R[9];
        compute_pose(threadIdx.x, state, phys, dts, t, R);
        float* o = sposes + threadIdx.x * 12;
        o[0] = t[0]; o[1] = t[1]; o[2] = t[2];
        for (int j = 0; j < 9; ++j) o[3 + j] = R[j];
    }

    // stage model features {-2g, |g|^2} for this chunk
    if (threadIdx.x < CHUNK) {
        int i = threadIdx.x;
        float gx = model[(mbase + i) * 3 + 0];
        float gy = model[(mbase + i) * 3 + 1];
        float gz = model[(mbase + i) * 3 + 2];
        sfeat[i] = make_float4(-2.0f * gx, -2.0f * gy, -2.0f * gz,
                               gx * gx + gy * gy + gz * gz);
    }
    __syncthreads();

    // transform this thread's 8 points: c = (p - t) @ R / SCALE
    float c0[PPT], c1[PPT], c2[PPT], cn[PPT], dm[PPT];
#pragma unroll
    for (int k = 0; k < PPT; ++k) {
        int pt = pb * PPB + k * TPB + threadIdx.x;
        int f = pt / PPF_;
        int loc = pt - f * PPF_;
        const float* p = (loc < NV_) ? (vis + ((size_t)f * NV_ + loc) * 3)
                                     : (tac + ((size_t)f * NT_ + (loc - NV_)) * 3);
        float px = p[0], py = p[1], pz = p[2];
        const float* ps = sposes + f * 12;
        float d0 = px - ps[0], d1 = py - ps[1], d2 = pz - ps[2];
        const float* R = ps + 3;
        float x = (d0 * R[0] + d1 * R[3] + d2 * R[6]) * SCALE_INV;
        float y = (d0 * R[1] + d1 * R[4] + d2 * R[7]) * SCALE_INV;
        float z = (d0 * R[2] + d1 * R[5] + d2 * R[8]) * SCALE_INV;
        c0[k] = x; c1[k] = y; c2[k] = z;
        cn[k] = x * x + y * y + z * z;
        dm[k] = 3.4e38f;
    }

    // min over chunk: track min(a.c + b); add |c|^2 once at the end
#pragma unroll 4
    for (int m = 0; m < CHUNK; m += 2) {
        float4 ga = sfeat[m];
        float4 gb = sfeat[m + 1];
#pragma unroll
        for (int k = 0; k < PPT; ++k) {
            float da = fmaf(ga.x, c0[k], fmaf(ga.y, c1[k], fmaf(ga.z, c2[k], ga.w)));
            float db = fmaf(gb.x, c0[k], fmaf(gb.y, c1[k], fmaf(gb.z, c2[k], gb.w)));
            dm[k] = fminf(dm[k], fminf(da, db));  // -> v_min3_f32
        }
    }

#pragma unroll
    for (int k = 0; k < PPT; ++k) {
        int pt = pb * PPB + k * TPB + threadIdx.x;
        partials[(size_t)ch * NPTS_ + pt] = dm[k] + cn[k];
    }
}

// ---------------------------------------------------------------- reduce
__global__ __launch_bounds__(TPB) void chamfer_reduce(
    const float* __restrict__ partials, float* __restrict__ out) {
    int pt = blockIdx.x * TPB + threadIdx.x;   // grid = NPTS_/TPB = 288
    float m = partials[pt];
    for (int ch = 1; ch < NCHUNK; ++ch)
        m = fminf(m, partials[(size_t)ch * NPTS_ + pt]);
    int loc = pt % PPF_;
    float w = (loc < NV_) ? (1.0f / NV_) : (0.1f / NT_);
    float v = m * w;
#pragma unroll
    for (int off = 32; off > 0; off >>= 1) v += __shfl_down(v, off);
    __shared__ float sw[TPB / 64];
    if ((threadIdx.x & 63) == 0) sw[threadIdx.x >> 6] = v;
    __syncthreads();
    if (threadIdx.x == 0) {
        float s = 0.0f;
        for (int i = 0; i < TPB / 64; ++i) s += sw[i];
        atomicAdd(out, s);
    }
}

// ---------------------------------------------------------------- zero-ws fallback
#define FB_PPT  2
#define FB_PPB  (TPB * FB_PPT)
#define FB_NPB  (NPTS_ / FB_PPB)   // 144 blocks

__global__ __launch_bounds__(TPB) void chamfer_fused(
    const float* __restrict__ state, const float* __restrict__ model,
    const float* __restrict__ vis, const float* __restrict__ tac,
    const float* __restrict__ phys, const float* __restrict__ dts,
    float* __restrict__ out) {
    __shared__ float4 sfeat[CHUNK];
    __shared__ float sposes[F_ * 12];
    __shared__ float sw[TPB / 64];

    if (threadIdx.x < F_) {
        float t[3], R[9];
        compute_pose(threadIdx.x, state, phys, dts, t, R);
        float* o = sposes + threadIdx.x * 12;
        o[0] = t[0]; o[1] = t[1]; o[2] = t[2];
        for (int j = 0; j < 9; ++j) o[3 + j] = R[j];
    }
    __syncthreads();

    float c0[FB_PPT], c1[FB_PPT], c2[FB_PPT], cn[FB_PPT], dm[FB_PPT], wt[FB_PPT];
#pragma unroll
    for (int k = 0; k < FB_PPT; ++k) {
        int pt = blockIdx.x * FB_PPB + k * TPB + threadIdx.x;
        int f = pt / PPF_;
        int loc = pt - f * PPF_;
        wt[k] = (loc < NV_) ? (1.0f / NV_) : (0.1f / NT_);
        const float* p = (loc < NV_) ? (vis + ((size_t)f * NV_ + loc) * 3)
                                     : (tac + ((size_t)f * NT_ + (loc - NV_)) * 3);
        float px = p[0], py = p[1], pz = p[2];
        const float* ps = sposes + f * 12;
        float d0 = px - ps[0], d1 = py - ps[1], d2 = pz - ps[2];
        const float* R = ps + 3;
        float x = (d0 * R[0] + d1 * R[3] + d2 * R[6]) * SCALE_INV;
        float y = (d0 * R[1] + d1 * R[4] + d2 * R[7]) * SCALE_INV;
        float z = (d0 * R[2] + d1 * R[5] + d2 * R[8]) * SCALE_INV;
        c0[k] = x; c1[k] = y; c2[k] = z;
        cn[k] = x * x + y * y + z * z;
        dm[k] = 3.4e38f;
    }

    for (int ch = 0; ch < NCHUNK; ++ch) {
        __syncthreads();
        if (threadIdx.x < CHUNK) {
            int i = threadIdx.x;
            int mi = ch * CHUNK + i;
            float gx = model[mi * 3 + 0], gy = model[mi * 3 + 1], gz = model[mi * 3 + 2];
            sfeat[i] = make_float4(-2.0f * gx, -2.0f * gy, -2.0f * gz,
                                   gx * gx + gy * gy + gz * gz);
        }
        __syncthreads();
#pragma unroll 4
        for (int m = 0; m < CHUNK; m += 2) {
            float4 ga = sfeat[m];
            float4 gb = sfeat[m + 1];
#pragma unroll
            for (int k = 0; k < FB_PPT; ++k) {
                float da = fmaf(ga.x, c0[k], fmaf(ga.y, c1[k], fmaf(ga.z, c2[k], ga.w)));
                float db = fmaf(gb.x, c0[k], fmaf(gb.y, c1[k], fmaf(gb.z, c2[k], gb.w)));
                dm[k] = fminf(dm[k], fminf(da, db));
            }
        }
    }

    float v = 0.0f;
#pragma unroll
    for (int k = 0; k < FB_PPT; ++k) v += (dm[k] + cn[k]) * wt[k];
#pragma unroll
    for (int off = 32; off > 0; off >>= 1) v += __shfl_down(v, off);
    if ((threadIdx.x & 63) == 0) sw[threadIdx.x >> 6] = v;
    __syncthreads();
    if (threadIdx.x == 0) {
        float s = 0.0f;
        for (int i = 0; i < TPB / 64; ++i) s += sw[i];
        atomicAdd(out, s);
    }
}

// ---------------------------------------------------------------- launch
extern "C" void kernel_launch(void* const* d_in, const int* in_sizes, int n_in,
                              void* d_out, int out_size, void* d_ws, size_t ws_size,
                              hipStream_t stream) {
    const float* state = (const float*)d_in[0];   // (6,)
    const float* model = (const float*)d_in[1];   // (M,3)
    const float* vis   = (const float*)d_in[2];   // (F,NV,3)
    const float* tac   = (const float*)d_in[3];   // (F,NT,3)
    const float* phys  = (const float*)d_in[4];   // (F,12)
    const float* dts   = (const float*)d_in[5];   // (F,)
    float* out = (float*)d_out;

    hipMemsetAsync(out, 0, sizeof(float), stream);

    const size_t partial_bytes = (size_t)NCHUNK * NPTS_ * sizeof(float);  // 9.4 MB

    if (ws_size >= partial_bytes) {
        float* partials = (float*)d_ws;
        dim3 grid(NPB, NCHUNK);
        chamfer_main<<<grid, TPB, 0, stream>>>(state, model, vis, tac, phys, dts,
                                               partials);
        chamfer_reduce<<<NPTS_ / TPB, TPB, 0, stream>>>(partials, out);
    } else {
        chamfer_fused<<<FB_NPB, TPB, 0, stream>>>(state, model, vis, tac, phys, dts,
                                                  out);
    }
}

// Round 3
// 103.937 us; speedup vs baseline: 1.1147x; 1.1147x over previous
//
#include <hip/hip_runtime.h>
#include <math.h>

#define F_    16
#define NV_   4096
#define NT_   512
#define M_    4096
#define PPF_  (NV_ + NT_)        // 4608 points per frame
#define NPTS_ (F_ * PPF_)        // 73728 total points
#define SCALE_INV 10.0f          // 1 / 0.1

#define TPB    256
#define PPT    8                 // points per thread (amortize LDS broadcast reads)
#define PPB    (TPB * PPT)       // 2048 points per block
#define NPB    (NPTS_ / PPB)     // 36 point-blocks
#define CHUNK  128               // model points per chunk
#define NCHUNK (M_ / CHUNK)      // 32 chunks -> grid 36x32 = 1152 blocks

// ---------------------------------------------------------------- pose math
__device__ inline void rot_from_omega(float ox, float oy, float oz, float dt,
                                      float* R) {
    // R = I + sin(theta*dt)*S + (1-cos(theta*dt))*S^2,  S = skew(omega/max(theta,1e-8))
    // S(a)^2 = a a^T - |a|^2 I  (valid for any a, matches literal S@S)
    float theta = sqrtf(ox * ox + oy * oy + oz * oz);
    float inv = 1.0f / fmaxf(theta, 1e-8f);
    float ax = ox * inv, ay = oy * inv, az = oz * inv;
    float s = sinf(theta * dt);
    float c = 1.0f - cosf(theta * dt);
    R[0] = 1.0f - c * (ay * ay + az * az);
    R[1] = -s * az + c * ax * ay;
    R[2] =  s * ay + c * ax * az;
    R[3] =  s * az + c * ax * ay;
    R[4] = 1.0f - c * (ax * ax + az * az);
    R[5] = -s * ax + c * ay * az;
    R[6] = -s * ax * 0.0f + c * 0.0f; // placeholder overwritten below (keep layout clear)
    R[6] = -s * ay + c * ax * az;
    R[7] =  s * ax + c * ay * az;
    R[8] = 1.0f - c * (ax * ax + ay * ay);
}

// 1-wave kernel. Threads 1..15 compute their step rotation (transcendentals in
// parallel); thread 0 then composes the 15-step chain serially (cheap FMAs only)
// and stores poses with R pre-scaled by 1/SCALE. Also zeroes the output scalar.
__global__ void pose_kernel(const float* __restrict__ state,
                            const float* __restrict__ phys,
                            const float* __restrict__ dts,
                            float* __restrict__ poses,
                            float* __restrict__ out) {
    __shared__ float sRs[F_ * 9];   // per-step rotations
    __shared__ float sdt[F_ * 3];   // per-step translation increments
    int f = threadIdx.x;
    if (f == 0) out[0] = 0.0f;
    if (f >= 1 && f < F_) {
        float Rs[9];
        float dt = dts[f];
        rot_from_omega(phys[f * 12 + 9], phys[f * 12 + 10], phys[f * 12 + 11], dt, Rs);
        for (int j = 0; j < 9; ++j) sRs[f * 9 + j] = Rs[j];
        sdt[f * 3 + 0] = phys[f * 12 + 6] * dt;
        sdt[f * 3 + 1] = phys[f * 12 + 7] * dt;
        sdt[f * 3 + 2] = phys[f * 12 + 8] * dt;
    }
    __syncthreads();
    if (f == 0) {
        float t[3] = {state[0], state[1], state[2]};
        float R[9];
        rot_from_omega(state[3], state[4], state[5], 1.0f, R);
        for (int i = 0; i < F_; ++i) {
            if (i > 0) {
                t[0] += sdt[i * 3 + 0];
                t[1] += sdt[i * 3 + 1];
                t[2] += sdt[i * 3 + 2];
                float Rn[9];
                const float* Rs = sRs + i * 9;
                for (int r = 0; r < 3; ++r)
                    for (int c2 = 0; c2 < 3; ++c2)
                        Rn[r * 3 + c2] = Rs[r * 3 + 0] * R[0 + c2] +
                                         Rs[r * 3 + 1] * R[3 + c2] +
                                         Rs[r * 3 + 2] * R[6 + c2];
                for (int j = 0; j < 9; ++j) R[j] = Rn[j];
            }
            float* o = poses + i * 12;
            o[0] = t[0]; o[1] = t[1]; o[2] = t[2];
            for (int j = 0; j < 9; ++j) o[3 + j] = R[j] * SCALE_INV;  // fold 1/SCALE
        }
    }
}

// ---------------------------------------------------------------- main kernel
// grid (NPB, NCHUNK). Each block: 2048 points x 128-model-point chunk.
// Writes per-chunk min distance to partials[ch][pt].
__global__ __launch_bounds__(TPB) void chamfer_main(
    const float* __restrict__ model, const float* __restrict__ vis,
    const float* __restrict__ tac, const float* __restrict__ poses,
    float* __restrict__ partials) {
    __shared__ float4 sfeat[CHUNK];
    __shared__ float sposes[F_ * 12];
    const int pb = blockIdx.x;
    const int ch = blockIdx.y;
    const int mbase = ch * CHUNK;

    if (threadIdx.x < F_ * 12) sposes[threadIdx.x] = poses[threadIdx.x];

    // stage model features {-2g, |g|^2} for this chunk
    if (threadIdx.x < CHUNK) {
        int i = threadIdx.x;
        float gx = model[(mbase + i) * 3 + 0];
        float gy = model[(mbase + i) * 3 + 1];
        float gz = model[(mbase + i) * 3 + 2];
        sfeat[i] = make_float4(-2.0f * gx, -2.0f * gy, -2.0f * gz,
                               gx * gx + gy * gy + gz * gz);
    }
    __syncthreads();

    // transform this thread's 8 points: c = (p - t) @ (R/SCALE)
    float c0[PPT], c1[PPT], c2[PPT], cn[PPT], dm[PPT];
#pragma unroll
    for (int k = 0; k < PPT; ++k) {
        int pt = pb * PPB + k * TPB + threadIdx.x;
        int f = pt / PPF_;
        int loc = pt - f * PPF_;
        const float* p = (loc < NV_) ? (vis + ((size_t)f * NV_ + loc) * 3)
                                     : (tac + ((size_t)f * NT_ + (loc - NV_)) * 3);
        float px = p[0], py = p[1], pz = p[2];
        const float* ps = sposes + f * 12;
        float d0 = px - ps[0], d1 = py - ps[1], d2 = pz - ps[2];
        const float* R = ps + 3;
        float x = d0 * R[0] + d1 * R[3] + d2 * R[6];
        float y = d0 * R[1] + d1 * R[4] + d2 * R[7];
        float z = d0 * R[2] + d1 * R[5] + d2 * R[8];
        c0[k] = x; c1[k] = y; c2[k] = z;
        cn[k] = x * x + y * y + z * z;
        dm[k] = 3.4e38f;
    }

    // min over chunk: track min(a.c + b); add |c|^2 once at the end
#pragma unroll 4
    for (int m = 0; m < CHUNK; m += 2) {
        float4 ga = sfeat[m];
        float4 gb = sfeat[m + 1];
#pragma unroll
        for (int k = 0; k < PPT; ++k) {
            float da = fmaf(ga.x, c0[k], fmaf(ga.y, c1[k], fmaf(ga.z, c2[k], ga.w)));
            float db = fmaf(gb.x, c0[k], fmaf(gb.y, c1[k], fmaf(gb.z, c2[k], gb.w)));
            dm[k] = fminf(dm[k], fminf(da, db));  // -> v_min3_f32
        }
    }

#pragma unroll
    for (int k = 0; k < PPT; ++k) {
        int pt = pb * PPB + k * TPB + threadIdx.x;
        partials[(size_t)ch * NPTS_ + pt] = dm[k] + cn[k];
    }
}

// ---------------------------------------------------------------- reduce
__global__ __launch_bounds__(TPB) void chamfer_reduce(
    const float* __restrict__ partials, float* __restrict__ out) {
    int pt = blockIdx.x * TPB + threadIdx.x;   // grid = NPTS_/TPB = 288
    float m = partials[pt];
    for (int ch = 1; ch < NCHUNK; ++ch)
        m = fminf(m, partials[(size_t)ch * NPTS_ + pt]);
    int loc = pt % PPF_;
    float w = (loc < NV_) ? (1.0f / NV_) : (0.1f / NT_);
    float v = m * w;
#pragma unroll
    for (int off = 32; off > 0; off >>= 1) v += __shfl_down(v, off);
    __shared__ float sw[TPB / 64];
    if ((threadIdx.x & 63) == 0) sw[threadIdx.x >> 6] = v;
    __syncthreads();
    if (threadIdx.x == 0) {
        float s = 0.0f;
        for (int i = 0; i < TPB / 64; ++i) s += sw[i];
        atomicAdd(out, s);
    }
}

// ---------------------------------------------------------------- zero-ws fallback
#define FB_PPT  2
#define FB_PPB  (TPB * FB_PPT)
#define FB_NPB  (NPTS_ / FB_PPB)   // 144 blocks

__device__ inline void compute_pose_serial(int f, const float* state,
                                           const float* phys, const float* dts,
                                           float* t, float* R) {
    t[0] = state[0]; t[1] = state[1]; t[2] = state[2];
    rot_from_omega(state[3], state[4], state[5], 1.0f, R);
    for (int i = 1; i <= f; ++i) {
        float dt = dts[i];
        t[0] += phys[i * 12 + 6] * dt;
        t[1] += phys[i * 12 + 7] * dt;
        t[2] += phys[i * 12 + 8] * dt;
        float Rs[9];
        rot_from_omega(phys[i * 12 + 9], phys[i * 12 + 10], phys[i * 12 + 11], dt, Rs);
        float Rn[9];
        for (int r = 0; r < 3; ++r)
            for (int c2 = 0; c2 < 3; ++c2)
                Rn[r * 3 + c2] = Rs[r * 3 + 0] * R[0 + c2] +
                                 Rs[r * 3 + 1] * R[3 + c2] +
                                 Rs[r * 3 + 2] * R[6 + c2];
        for (int j = 0; j < 9; ++j) R[j] = Rn[j];
    }
}

__global__ __launch_bounds__(TPB) void chamfer_fused(
    const float* __restrict__ state, const float* __restrict__ model,
    const float* __restrict__ vis, const float* __restrict__ tac,
    const float* __restrict__ phys, const float* __restrict__ dts,
    float* __restrict__ out) {
    __shared__ float4 sfeat[CHUNK];
    __shared__ float sposes[F_ * 12];
    __shared__ float sw[TPB / 64];

    if (threadIdx.x < F_) {
        float t[3], R[9];
        compute_pose_serial(threadIdx.x, state, phys, dts, t, R);
        float* o = sposes + threadIdx.x * 12;
        o[0] = t[0]; o[1] = t[1]; o[2] = t[2];
        for (int j = 0; j < 9; ++j) o[3 + j] = R[j] * SCALE_INV;
    }
    __syncthreads();

    float c0[FB_PPT], c1[FB_PPT], c2[FB_PPT], cn[FB_PPT], dm[FB_PPT], wt[FB_PPT];
#pragma unroll
    for (int k = 0; k < FB_PPT; ++k) {
        int pt = blockIdx.x * FB_PPB + k * TPB + threadIdx.x;
        int f = pt / PPF_;
        int loc = pt - f * PPF_;
        wt[k] = (loc < NV_) ? (1.0f / NV_) : (0.1f / NT_);
        const float* p = (loc < NV_) ? (vis + ((size_t)f * NV_ + loc) * 3)
                                     : (tac + ((size_t)f * NT_ + (loc - NV_)) * 3);
        float px = p[0], py = p[1], pz = p[2];
        const float* ps = sposes + f * 12;
        float d0 = px - ps[0], d1 = py - ps[1], d2 = pz - ps[2];
        const float* R = ps + 3;
        float x = d0 * R[0] + d1 * R[3] + d2 * R[6];
        float y = d0 * R[1] + d1 * R[4] + d2 * R[7];
        float z = d0 * R[2] + d1 * R[5] + d2 * R[8];
        c0[k] = x; c1[k] = y; c2[k] = z;
        cn[k] = x * x + y * y + z * z;
        dm[k] = 3.4e38f;
    }

    for (int ch = 0; ch < NCHUNK; ++ch) {
        __syncthreads();
        if (threadIdx.x < CHUNK) {
            int i = threadIdx.x;
            int mi = ch * CHUNK + i;
            float gx = model[mi * 3 + 0], gy = model[mi * 3 + 1], gz = model[mi * 3 + 2];
            sfeat[i] = make_float4(-2.0f * gx, -2.0f * gy, -2.0f * gz,
                                   gx * gx + gy * gy + gz * gz);
        }
        __syncthreads();
#pragma unroll 4
        for (int m = 0; m < CHUNK; m += 2) {
            float4 ga = sfeat[m];
            float4 gb = sfeat[m + 1];
#pragma unroll
            for (int k = 0; k < FB_PPT; ++k) {
                float da = fmaf(ga.x, c0[k], fmaf(ga.y, c1[k], fmaf(ga.z, c2[k], ga.w)));
                float db = fmaf(gb.x, c0[k], fmaf(gb.y, c1[k], fmaf(gb.z, c2[k], gb.w)));
                dm[k] = fminf(dm[k], fminf(da, db));
            }
        }
    }

    float v = 0.0f;
#pragma unroll
    for (int k = 0; k < FB_PPT; ++k) v += (dm[k] + cn[k]) * wt[k];
#pragma unroll
    for (int off = 32; off > 0; off >>= 1) v += __shfl_down(v, off);
    if ((threadIdx.x & 63) == 0) sw[threadIdx.x >> 6] = v;
    __syncthreads();
    if (threadIdx.x == 0) {
        float s = 0.0f;
        for (int i = 0; i < TPB / 64; ++i) s += sw[i];
        atomicAdd(out, s);
    }
}

// ---------------------------------------------------------------- launch
extern "C" void kernel_launch(void* const* d_in, const int* in_sizes, int n_in,
                              void* d_out, int out_size, void* d_ws, size_t ws_size,
                              hipStream_t stream) {
    const float* state = (const float*)d_in[0];   // (6,)
    const float* model = (const float*)d_in[1];   // (M,3)
    const float* vis   = (const float*)d_in[2];   // (F,NV,3)
    const float* tac   = (const float*)d_in[3];   // (F,NT,3)
    const float* phys  = (const float*)d_in[4];   // (F,12)
    const float* dts   = (const float*)d_in[5];   // (F,)
    float* out = (float*)d_out;

    const size_t partial_bytes = (size_t)NCHUNK * NPTS_ * sizeof(float);  // 9.4 MB
    const size_t need = partial_bytes + F_ * 12 * sizeof(float);

    if (ws_size >= need) {
        float* partials = (float*)d_ws;
        float* poses = (float*)((char*)d_ws + partial_bytes);
        pose_kernel<<<1, 64, 0, stream>>>(state, phys, dts, poses, out);
        dim3 grid(NPB, NCHUNK);
        chamfer_main<<<grid, TPB, 0, stream>>>(model, vis, tac, poses, partials);
        chamfer_reduce<<<NPTS_ / TPB, TPB, 0, stream>>>(partials, out);
    } else {
        hipMemsetAsync(out, 0, sizeof(float), stream);
        chamfer_fused<<<FB_NPB, TPB, 0, stream>>>(state, model, vis, tac, phys, dts,
                                                  out);
    }
}